// Round 2
// 164.050 us; speedup vs baseline: 1.0436x; 1.0436x over previous
//
#include <hip/hip_runtime.h>
#include <stdint.h>

#define IN_DIM 512
#define CB 8192
#define CD 16
#define NROWS 32768
#define DELTAQ 8e-3f
#define FMAXV 3.402823466e38f

typedef short bf16x8 __attribute__((ext_vector_type(8)));
typedef float f32x4 __attribute__((ext_vector_type(4)));

__device__ inline unsigned short f2bf(float x) {
    unsigned u = __float_as_uint(x);
    unsigned r = u + 0x7FFFu + ((u >> 16) & 1u);   // RNE
    return (unsigned short)(r >> 16);
}
__device__ inline float bf2f(unsigned short h) { return __uint_as_float(((unsigned)h) << 16); }
__device__ inline unsigned umin32(unsigned a, unsigned b) { return a < b ? a : b; }
__device__ inline unsigned umax32(unsigned a, unsigned b) { return a > b ? a : b; }
__device__ inline unsigned long long shfl_xor_u64(unsigned long long x, int m) {
    double d = __shfl_xor(__longlong_as_double((long long)x), m, 64);
    return (unsigned long long)__double_as_longlong(d);
}
// median(a,b,c): with invariant s1<=s2, med3(s1,s2,k) == umin(s2, umax(k, s1)) bit-exactly.
__device__ inline unsigned med3_u32(unsigned a, unsigned b, unsigned c) {
    unsigned d;
    asm("v_med3_u32 %0, %1, %2, %3" : "=v"(d) : "v"(a), "v"(b), "v"(c));
    return d;
}

// ---------------- K0 (fused): blocks [0,2048) = proj partials, blocks [2048,2176) = prep ----------------
// prep: csq (R1-bit-exact) + csq4 = broadcast {csq+256} f32x4 table + packed B fragments + counter reset.
// proj: sacred DAG, pure-LDS inner loop, unchanged from prior verified kernel.
__global__ __launch_bounds__(256) void prep_proj_kernel(const float* __restrict__ in,
                                                        const float* __restrict__ W,
                                                        float* __restrict__ partials,
                                                        const float* __restrict__ cb,
                                                        float* __restrict__ csq,
                                                        f32x4* __restrict__ csq4,
                                                        bf16x8* __restrict__ Bp,
                                                        int* __restrict__ counter) {
    __shared__ float4 LIN[2048];        // [o=0..31][r=0..63] swizzled
    __shared__ float4 WL[16 * 33];      // [d][j] with pad: row stride 33 f4
    int tid = threadIdx.x;

    if (blockIdx.x >= 2048) {
        // ---------------- prep branch ----------------
        int id = (blockIdx.x - 2048) * 256 + tid;  // 0..32767
        if (id == 0) counter[0] = 0;
        if (id < CB) {   // SOURCE-IDENTICAL csq expression (bit-exact vs R1)
            const float4* p = (const float4*)(cb + (size_t)id * CD);
            float s = 0.f;
#pragma unroll
            for (int j = 0; j < 4; ++j) {
                float4 v = p[j];
                s += v.x * v.x + v.y * v.y + v.z * v.z + v.w * v.w;
            }
            csq[id] = s;
            float so = s + 256.0f;     // positive-score offset (approx path only)
            f32x4 v4 = {so, so, so, so};
            csq4[id] = v4;             // pre-broadcast MFMA C-operand, 1 dwordx4 load in scan
        }
        int slot = id & 63;
        int nt = id >> 6;
        int q = slot >> 4;
        int n = nt * 16 + (slot & 15);
        int d0 = (q & 1) * 8;
        bool lo = (q < 2);          // k<16 -> c1[d], k>=16 -> c2[d]
        const float* src = cb + (size_t)n * CD + d0;
        bf16x8 v;
#pragma unroll
        for (int j = 0; j < 8; ++j) {
            float x = src[j];
            unsigned short a = f2bf(x);
            unsigned short b = f2bf(x - bf2f(a));
            v[j] = (short)(lo ? a : b);
        }
        Bp[id] = v;
        return;
    }

    // ---------------- proj branch (unchanged sacred DAG) ----------------
    int lane = tid & 63;
    int dg = __builtin_amdgcn_readfirstlane(tid >> 6);   // d-group: d in [4dg, 4dg+4)
    int strip = blockIdx.x >> 2;
    int c = blockIdx.x & 3;
    int rowbase = strip * 64;
    const float4* inp4 = (const float4*)in;
    const float4* W4 = (const float4*)W;

    // stage W slice: d rows 0..15, chunk c: 16 x 32 f4
#pragma unroll
    for (int u = 0; u < 2; ++u) {
        int f = tid + u * 256;          // 0..511
        int d = f >> 5, o = f & 31;
        WL[d * 33 + o] = W4[(size_t)d * 128 + c * 32 + o];
    }
    // stage input chunk: 64 rows x 32 f4, transposed-swizzled
#pragma unroll
    for (int u = 0; u < 8; ++u) {
        int f = tid + u * 256;          // 0..2047
        int o = f & 31, r = f >> 5;     // consecutive tid -> consecutive o: global coalesced
        LIN[o * 64 + (r ^ (o & 7))] = inp4[(size_t)(rowbase + r) * 128 + c * 32 + o];
    }
    __syncthreads();

    float acc[4];
#pragma unroll
    for (int i = 0; i < 4; ++i) acc[i] = 0.f;
#pragma unroll 4
    for (int j = 0; j < 32; ++j) {
        float4 v = LIN[j * 64 + (lane ^ (j & 7))];
#pragma unroll
        for (int i = 0; i < 4; ++i) {
            float4 w = WL[(4 * dg + i) * 33 + j];   // wave-uniform -> LDS broadcast
            acc[i] += v.x * w.x + v.y * w.y + v.z * w.z + v.w * w.w;
        }
    }
    float* o = partials + (size_t)c * NROWS * CD + (size_t)(rowbase + lane) * CD + 4 * dg;
#pragma unroll
    for (int i = 0; i < 4; ++i) o[i] = acc[i];
}

// ---------------- K2: packed-B scan + inline combine; med3 second-min; f32x4 C-operand load ----------------
// 1024 blocks x 512 thr; 32 rows/block (G=2); wave e scans eighth e (64 tiles).
__global__ __launch_bounds__(512, 6) void scan_kernel(
        const float* __restrict__ partials, const f32x4* __restrict__ csq4,
        const bf16x8* __restrict__ Bp, int* __restrict__ out,
        int* __restrict__ queue, int* __restrict__ counter) {
    __shared__ float tbuf[32][17];
    __shared__ unsigned long long m_k[32][8];
    __shared__ unsigned m_s2[32][8];

    int tid = threadIdx.x;
    int lane = tid & 63;
    int e = __builtin_amdgcn_readfirstlane(tid >> 6);   // eighth 0..7
    int rowbase = blockIdx.x * 32;

    {   // inline combine: ((c0+c1)+c2)+c3 fold, *(-2) — bit-exact lineage of prior K1b
        int rr = tid >> 4, d = tid & 15;
        size_t idx = (size_t)(rowbase + rr) * CD + d;
        const size_t P = (size_t)NROWS * CD;
        float p0 = partials[idx];
        float p1 = partials[P + idx];
        float p2 = partials[2 * P + idx];
        float p3 = partials[3 * P + idx];
        tbuf[rr][d] = -2.f * (((p0 + p1) + p2) + p3);
    }
    __syncthreads();

    int q = lane >> 4;
    int col = lane & 15;
    int d0 = (q & 1) * 8;
    bool lo = (q < 2);

    bf16x8 A1[2], A2[2];   // per rowgroup: A1=[t1|t1], A2=[t2|0]
#pragma unroll
    for (int g = 0; g < 2; ++g) {
        int arow = 16 * g + col;
#pragma unroll
        for (int j = 0; j < 8; ++j) {
            float x = tbuf[arow][d0 + j];
            unsigned short t1 = f2bf(x);
            unsigned short t2 = f2bf(x - bf2f(t1));
            A1[g][j] = (short)t1;
            A2[g][j] = (short)(lo ? t2 : 0);
        }
    }

    unsigned s1[2][4], s2[2][4];
#pragma unroll
    for (int g = 0; g < 2; ++g)
#pragma unroll
        for (int r = 0; r < 4; ++r) { s1[g][r] = 0xFFFFFFFFu; s2[g][r] = 0xFFFFFFFFu; }

    int nt0 = e * 64;
    const bf16x8* pb = Bp + (size_t)nt0 * 64 + lane;
    const f32x4* csqp = csq4 + nt0 * 16 + col;

#pragma unroll 8
    for (int t = 0; t < 64; ++t) {
        bf16x8 b = pb[(size_t)t * 64];
        f32x4 ini = csqp[t * 16];       // {cs,cs,cs,cs} straight into the C-operand regs
        unsigned tt = (unsigned)t;
#pragma unroll
        for (int g = 0; g < 2; ++g) {
            f32x4 acc = __builtin_amdgcn_mfma_f32_16x16x32_bf16(A1[g], b, ini, 0, 0, 0);
            acc = __builtin_amdgcn_mfma_f32_16x16x32_bf16(A2[g], b, acc, 0, 0, 0);
#pragma unroll
            for (int r = 0; r < 4; ++r) {
                unsigned k = (__float_as_uint(acc[r]) & 0xFFFFFFC0u) | tt;
                s2[g][r] = med3_u32(s1[g][r], s2[g][r], k);  // == umin(s2, umax(k, OLD s1))
                s1[g][r] = umin32(s1[g][r], k);
            }
        }
    }

    // cross-col reduce; FK orders (qscore, e, tile, col) = (qscore, code)
#pragma unroll
    for (int g = 0; g < 2; ++g)
#pragma unroll
        for (int r = 0; r < 4; ++r) {
            unsigned long long FK = ((unsigned long long)(s1[g][r] & 0xFFFFFFC0u) << 13)
                                  | ((unsigned long long)e << 10)
                                  | ((unsigned long long)(s1[g][r] & 63u) << 4)
                                  | (unsigned long long)col;
            unsigned s2q = s2[g][r] & 0xFFFFFFC0u;
#pragma unroll
            for (int m = 1; m < 16; m <<= 1) {
                unsigned long long oFK = shfl_xor_u64(FK, m);
                unsigned os2 = (unsigned)__shfl_xor((int)s2q, m, 64);
                unsigned qa = (unsigned)(FK >> 13);
                unsigned qb = (unsigned)(oFK >> 13);
                s2q = umin32(umin32(s2q, os2), umax32(qa, qb));
                FK = oFK < FK ? oFK : FK;
            }
            if (col == 0) {
                int rl = 16 * g + 4 * q + r;   // C/D row = quad*4 + reg
                m_k[rl][e] = FK;
                m_s2[rl][e] = s2q;
            }
        }
    __syncthreads();

    if (tid < 32) {
        unsigned long long mFK = m_k[tid][0];
        unsigned g1 = (unsigned)(m_k[tid][0] >> 13);
        unsigned g2 = m_s2[tid][0];
#pragma unroll
        for (int ee = 1; ee < 8; ++ee) {
            unsigned long long F = m_k[tid][ee];
            unsigned u = (unsigned)(F >> 13);
            if (u < g1) { g2 = g1; g1 = u; } else { g2 = umin32(g2, u); }
            g2 = umin32(g2, m_s2[tid][ee]);
            mFK = F < mFK ? F : mFK;
        }
        int ccol = (int)(mFK & 15ull);
        int ctile = (int)((mFK >> 4) & 63ull);
        int ce = (int)((mFK >> 10) & 7ull);
        int row = rowbase + tid;
        out[row] = ((ce * 64 + ctile) << 4) | ccol;
        if (__uint_as_float(g2) - __uint_as_float(g1) < DELTAQ) {
            int pos = atomicAdd(counter, 1);
            queue[pos] = row;
        }
    }
}

// ---------------- K3: fallback — R1's fp32 arithmetic, bit-exact, queue-driven, wide grid ----------------
__global__ __launch_bounds__(256) void fallback_kernel(const float* __restrict__ partials,
                                                       const float* __restrict__ cb,
                                                       const float* __restrict__ csq,
                                                       const int* __restrict__ queue,
                                                       const int* __restrict__ counter,
                                                       int* __restrict__ out) {
    __shared__ unsigned long long red[4];
    int nq = counter[0];
    int tid = threadIdx.x;
    int lane = tid & 63;
    int w = tid >> 6;

    for (int qi = blockIdx.x; qi < nq; qi += 2048) {
        int row = queue[qi];
        const size_t P = (size_t)NROWS * CD;
        size_t base = (size_t)row * CD;
        float tp[16];
#pragma unroll
        for (int d = 0; d < 16; ++d)   // inline combine, identical fold -> bit-exact tprime
            tp[d] = -2.f * (((partials[base + d] + partials[P + base + d])
                             + partials[2 * P + base + d]) + partials[3 * P + base + d]);

        float best = FMAXV;
        int bidx = 0;
#pragma unroll 2
        for (int i = 0; i < 32; ++i) {
            int k = tid + 256 * i;            // ascending per thread
            const float* cp = cb + (size_t)k * CD;
            float s = csq[k];
#pragma unroll
            for (int d = 0; d < 16; ++d) s += tp[d] * cp[d];
            if (s < best) { best = s; bidx = k; }
        }
        unsigned u = __float_as_uint(best);
        u = (u & 0x80000000u) ? ~u : (u | 0x80000000u);
        unsigned long long key = ((unsigned long long)u << 32) | (unsigned)bidx;
#pragma unroll
        for (int m = 1; m < 64; m <<= 1) {
            unsigned long long o = shfl_xor_u64(key, m);
            key = o < key ? o : key;
        }
        if (lane == 0) red[w] = key;
        __syncthreads();
        if (tid == 0) {
            unsigned long long mm = red[0];
#pragma unroll
            for (int i = 1; i < 4; ++i) { unsigned long long x = red[i]; mm = x < mm ? x : mm; }
            out[row] = (int)(mm & 0xFFFFFFFFull);
        }
        __syncthreads();
    }
}

extern "C" void kernel_launch(void* const* d_in, const int* in_sizes, int n_in,
                              void* d_out, int out_size, void* d_ws, size_t ws_size,
                              hipStream_t stream) {
    const float* input = (const float*)d_in[0];  // (8,4096,512) fp32
    const float* W     = (const float*)d_in[1];  // (16,512) fp32
    const float* cb    = (const float*)d_in[2];  // (8192,16) fp32
    int* out = (int*)d_out;                      // (32768,) int32 labels

    float*  partials = (float*)d_ws;                        // 8 MB
    float*  csq      = partials + 4 * (size_t)NROWS * CD;   // 32 KB
    f32x4*  csq4     = (f32x4*)(csq + CB);                  // 128 KB
    bf16x8* Bp       = (bf16x8*)((float*)csq4 + 4 * CB);    // 512 KB
    int*    counter  = (int*)(Bp + 32768);
    int*    queue    = counter + 16;                        // 128 KB

    prep_proj_kernel<<<2176, 256, 0, stream>>>(input, W, partials, cb, csq, csq4, Bp, counter);
    scan_kernel<<<NROWS / 32, 512, 0, stream>>>(partials, csq4, Bp, out, queue, counter);
    fallback_kernel<<<2048, 256, 0, stream>>>(partials, cb, csq, queue, counter, out);
}

// Round 4
// 162.758 us; speedup vs baseline: 1.0518x; 1.0079x over previous
//
#include <hip/hip_runtime.h>
#include <stdint.h>

#define IN_DIM 512
#define CB 8192
#define CD 16
#define NROWS 32768
#define DELTAQ 8e-3f
#define FMAXV 3.402823466e38f

typedef short bf16x8 __attribute__((ext_vector_type(8)));
typedef float f32x4 __attribute__((ext_vector_type(4)));

__device__ inline unsigned short f2bf(float x) {
    unsigned u = __float_as_uint(x);
    unsigned r = u + 0x7FFFu + ((u >> 16) & 1u);   // RNE
    return (unsigned short)(r >> 16);
}
__device__ inline float bf2f(unsigned short h) { return __uint_as_float(((unsigned)h) << 16); }
__device__ inline unsigned umin32(unsigned a, unsigned b) { return a < b ? a : b; }
__device__ inline unsigned umax32(unsigned a, unsigned b) { return a > b ? a : b; }
__device__ inline unsigned long long shfl_xor_u64(unsigned long long x, int m) {
    double d = __shfl_xor(__longlong_as_double((long long)x), m, 64);
    return (unsigned long long)__double_as_longlong(d);
}
// median(a,b,c): with invariant s1<=s2, med3(s1,s2,k) == umin(s2, umax(k, s1)) bit-exactly.
__device__ inline unsigned med3_u32(unsigned a, unsigned b, unsigned c) {
    unsigned d;
    asm("v_med3_u32 %0, %1, %2, %3" : "=v"(d) : "v"(a), "v"(b), "v"(c));
    return d;
}

// ---------------- K0 (fused): blocks [0,2048) = proj partials, blocks [2048,2176) = prep ----------------
// prep: csq (R1-bit-exact) + csq4 = broadcast {csq+256} f32x4 table + packed B fragments + counter reset.
// proj: sacred DAG, pure-LDS inner loop, unchanged from prior verified kernel.
__global__ __launch_bounds__(256) void prep_proj_kernel(const float* __restrict__ in,
                                                        const float* __restrict__ W,
                                                        float* __restrict__ partials,
                                                        const float* __restrict__ cb,
                                                        float* __restrict__ csq,
                                                        f32x4* __restrict__ csq4,
                                                        bf16x8* __restrict__ Bp,
                                                        int* __restrict__ counter) {
    __shared__ float4 LIN[2048];        // [o=0..31][r=0..63] swizzled
    __shared__ float4 WL[16 * 33];      // [d][j] with pad: row stride 33 f4
    int tid = threadIdx.x;

    if (blockIdx.x >= 2048) {
        // ---------------- prep branch ----------------
        int id = (blockIdx.x - 2048) * 256 + tid;  // 0..32767
        if (id == 0) counter[0] = 0;
        if (id < CB) {   // SOURCE-IDENTICAL csq expression (bit-exact vs R1)
            const float4* p = (const float4*)(cb + (size_t)id * CD);
            float s = 0.f;
#pragma unroll
            for (int j = 0; j < 4; ++j) {
                float4 v = p[j];
                s += v.x * v.x + v.y * v.y + v.z * v.z + v.w * v.w;
            }
            csq[id] = s;
            float so = s + 256.0f;     // positive-score offset (approx path only)
            f32x4 v4 = {so, so, so, so};
            csq4[id] = v4;             // pre-broadcast MFMA C-operand, 1 dwordx4 load in scan
        }
        int slot = id & 63;
        int nt = id >> 6;
        int q = slot >> 4;
        int n = nt * 16 + (slot & 15);
        int d0 = (q & 1) * 8;
        bool lo = (q < 2);          // k<16 -> c1[d], k>=16 -> c2[d]
        const float* src = cb + (size_t)n * CD + d0;
        bf16x8 v;
#pragma unroll
        for (int j = 0; j < 8; ++j) {
            float x = src[j];
            unsigned short a = f2bf(x);
            unsigned short b = f2bf(x - bf2f(a));
            v[j] = (short)(lo ? a : b);
        }
        Bp[id] = v;
        return;
    }

    // ---------------- proj branch (unchanged sacred DAG) ----------------
    int lane = tid & 63;
    int dg = __builtin_amdgcn_readfirstlane(tid >> 6);   // d-group: d in [4dg, 4dg+4)
    int strip = blockIdx.x >> 2;
    int c = blockIdx.x & 3;
    int rowbase = strip * 64;
    const float4* inp4 = (const float4*)in;
    const float4* W4 = (const float4*)W;

    // stage W slice: d rows 0..15, chunk c: 16 x 32 f4
#pragma unroll
    for (int u = 0; u < 2; ++u) {
        int f = tid + u * 256;          // 0..511
        int d = f >> 5, o = f & 31;
        WL[d * 33 + o] = W4[(size_t)d * 128 + c * 32 + o];
    }
    // stage input chunk: 64 rows x 32 f4, transposed-swizzled
#pragma unroll
    for (int u = 0; u < 8; ++u) {
        int f = tid + u * 256;          // 0..2047
        int o = f & 31, r = f >> 5;     // consecutive tid -> consecutive o: global coalesced
        LIN[o * 64 + (r ^ (o & 7))] = inp4[(size_t)(rowbase + r) * 128 + c * 32 + o];
    }
    __syncthreads();

    float acc[4];
#pragma unroll
    for (int i = 0; i < 4; ++i) acc[i] = 0.f;
#pragma unroll 4
    for (int j = 0; j < 32; ++j) {
        float4 v = LIN[j * 64 + (lane ^ (j & 7))];
#pragma unroll
        for (int i = 0; i < 4; ++i) {
            float4 w = WL[(4 * dg + i) * 33 + j];   // wave-uniform -> LDS broadcast
            acc[i] += v.x * w.x + v.y * w.y + v.z * w.z + v.w * w.w;
        }
    }
    float* o = partials + (size_t)c * NROWS * CD + (size_t)(rowbase + lane) * CD + 4 * dg;
#pragma unroll
    for (int i = 0; i < 4; ++i) o[i] = acc[i];
}

// ---------------- K2: packed-B scan, G=4 rowgroups (64 rows/block), chunked loads ----------------
// 512 blocks x 512 thr; wave e scans eighth e (64 tiles). Each b/ini load feeds 8 MFMAs.
// launch_bounds(512,4): VGPR ceiling 128 -> chunk-staged loads + 4 independent MFMA chains (ILP).
__global__ __launch_bounds__(512, 4) void scan_kernel(
        const float* __restrict__ partials, const f32x4* __restrict__ csq4,
        const bf16x8* __restrict__ Bp, int* __restrict__ out,
        int* __restrict__ queue, int* __restrict__ counter) {
    __shared__ float tbuf[64][17];
    __shared__ unsigned long long m_k[64][8];
    __shared__ unsigned m_s2[64][8];

    int tid = threadIdx.x;
    int lane = tid & 63;
    int e = __builtin_amdgcn_readfirstlane(tid >> 6);   // eighth 0..7
    int rowbase = blockIdx.x * 64;

    // inline combine: ((c0+c1)+c2)+c3 fold, *(-2) — bit-exact lineage
#pragma unroll
    for (int u = 0; u < 2; ++u) {
        int f = tid + u * 512;          // 0..1023
        int rr = f >> 4, d = f & 15;
        size_t idx = (size_t)(rowbase + rr) * CD + d;
        const size_t P = (size_t)NROWS * CD;
        float p0 = partials[idx];
        float p1 = partials[P + idx];
        float p2 = partials[2 * P + idx];
        float p3 = partials[3 * P + idx];
        tbuf[rr][d] = -2.f * (((p0 + p1) + p2) + p3);
    }
    __syncthreads();

    int q = lane >> 4;
    int col = lane & 15;
    int d0 = (q & 1) * 8;
    bool lo = (q < 2);

    bf16x8 A1[4], A2[4];   // per rowgroup: A1=[t1|t1], A2=[t2|0]
#pragma unroll
    for (int g = 0; g < 4; ++g) {
        int arow = 16 * g + col;
#pragma unroll
        for (int j = 0; j < 8; ++j) {
            float x = tbuf[arow][d0 + j];
            unsigned short t1 = f2bf(x);
            unsigned short t2 = f2bf(x - bf2f(t1));
            A1[g][j] = (short)t1;
            A2[g][j] = (short)(lo ? t2 : 0);
        }
    }

    unsigned s1[4][4], s2[4][4];
#pragma unroll
    for (int g = 0; g < 4; ++g)
#pragma unroll
        for (int r = 0; r < 4; ++r) { s1[g][r] = 0xFFFFFFFFu; s2[g][r] = 0xFFFFFFFFu; }

    int nt0 = e * 64;
    const bf16x8* pb = Bp + (size_t)nt0 * 64 + lane;
    const f32x4* csqp = csq4 + nt0 * 16 + col;

    // 16 chunks x 4 tiles; explicit pointer bump per chunk so all global offsets
    // fold into 13-bit immediates (b: 0/1/2/3 KB, ini: 0/256/512/768 B).
    for (int tc = 0; tc < 16; ++tc) {
        bf16x8 bv[4];
        f32x4 iv[4];
#pragma unroll
        for (int u = 0; u < 4; ++u) {
            bv[u] = pb[u * 64];
            iv[u] = csqp[u * 16];
        }
#pragma unroll
        for (int u = 0; u < 4; ++u) {
            unsigned tt = (unsigned)(tc * 4 + u);
#pragma unroll
            for (int g = 0; g < 4; ++g) {   // 4 independent MFMA-pair chains per b
                f32x4 acc = __builtin_amdgcn_mfma_f32_16x16x32_bf16(A1[g], bv[u], iv[u], 0, 0, 0);
                acc = __builtin_amdgcn_mfma_f32_16x16x32_bf16(A2[g], bv[u], acc, 0, 0, 0);
#pragma unroll
                for (int r = 0; r < 4; ++r) {
                    unsigned k = (__float_as_uint(acc[r]) & 0xFFFFFFC0u) | tt;
                    s2[g][r] = med3_u32(s1[g][r], s2[g][r], k);  // == umin(s2, umax(k, OLD s1))
                    s1[g][r] = umin32(s1[g][r], k);
                }
            }
        }
        pb += 256;     // 4 tiles * 64 fragments
        csqp += 64;    // 4 tiles * 16 cols
    }

    // cross-col reduce; FK orders (qscore, e, tile, col) = (qscore, code)
#pragma unroll
    for (int g = 0; g < 4; ++g)
#pragma unroll
        for (int r = 0; r < 4; ++r) {
            unsigned long long FK = ((unsigned long long)(s1[g][r] & 0xFFFFFFC0u) << 13)
                                  | ((unsigned long long)e << 10)
                                  | ((unsigned long long)(s1[g][r] & 63u) << 4)
                                  | (unsigned long long)col;
            unsigned s2q = s2[g][r] & 0xFFFFFFC0u;
#pragma unroll
            for (int m = 1; m < 16; m <<= 1) {
                unsigned long long oFK = shfl_xor_u64(FK, m);
                unsigned os2 = (unsigned)__shfl_xor((int)s2q, m, 64);
                unsigned qa = (unsigned)(FK >> 13);
                unsigned qb = (unsigned)(oFK >> 13);
                s2q = umin32(umin32(s2q, os2), umax32(qa, qb));
                FK = oFK < FK ? oFK : FK;
            }
            if (col == 0) {
                int rl = 16 * g + 4 * q + r;   // C/D row = quad*4 + reg; rl in 0..63
                m_k[rl][e] = FK;
                m_s2[rl][e] = s2q;
            }
        }
    __syncthreads();

    if (tid < 64) {
        unsigned long long mFK = m_k[tid][0];
        unsigned g1 = (unsigned)(m_k[tid][0] >> 13);
        unsigned g2 = m_s2[tid][0];
#pragma unroll
        for (int ee = 1; ee < 8; ++ee) {
            unsigned long long F = m_k[tid][ee];
            unsigned u = (unsigned)(F >> 13);
            if (u < g1) { g2 = g1; g1 = u; } else { g2 = umin32(g2, u); }
            g2 = umin32(g2, m_s2[tid][ee]);
            mFK = F < mFK ? F : mFK;
        }
        int ccol = (int)(mFK & 15ull);
        int ctile = (int)((mFK >> 4) & 63ull);
        int ce = (int)((mFK >> 10) & 7ull);
        int row = rowbase + tid;
        out[row] = ((ce * 64 + ctile) << 4) | ccol;
        if (__uint_as_float(g2) - __uint_as_float(g1) < DELTAQ) {
            int pos = atomicAdd(counter, 1);
            queue[pos] = row;
        }
    }
}

// ---------------- K3: fallback — R1's fp32 arithmetic, bit-exact, queue-driven, wide grid ----------------
__global__ __launch_bounds__(256) void fallback_kernel(const float* __restrict__ partials,
                                                       const float* __restrict__ cb,
                                                       const float* __restrict__ csq,
                                                       const int* __restrict__ queue,
                                                       const int* __restrict__ counter,
                                                       int* __restrict__ out) {
    __shared__ unsigned long long red[4];
    int nq = counter[0];
    int tid = threadIdx.x;
    int lane = tid & 63;
    int w = tid >> 6;

    for (int qi = blockIdx.x; qi < nq; qi += 2048) {
        int row = queue[qi];
        const size_t P = (size_t)NROWS * CD;
        size_t base = (size_t)row * CD;
        float tp[16];
#pragma unroll
        for (int d = 0; d < 16; ++d)   // inline combine, identical fold -> bit-exact tprime
            tp[d] = -2.f * (((partials[base + d] + partials[P + base + d])
                             + partials[2 * P + base + d]) + partials[3 * P + base + d]);

        float best = FMAXV;
        int bidx = 0;
#pragma unroll 2
        for (int i = 0; i < 32; ++i) {
            int k = tid + 256 * i;            // ascending per thread
            const float* cp = cb + (size_t)k * CD;
            float s = csq[k];
#pragma unroll
            for (int d = 0; d < 16; ++d) s += tp[d] * cp[d];
            if (s < best) { best = s; bidx = k; }
        }
        unsigned u = __float_as_uint(best);
        u = (u & 0x80000000u) ? ~u : (u | 0x80000000u);
        unsigned long long key = ((unsigned long long)u << 32) | (unsigned)bidx;
#pragma unroll
        for (int m = 1; m < 64; m <<= 1) {
            unsigned long long o = shfl_xor_u64(key, m);
            key = o < key ? o : key;
        }
        if (lane == 0) red[w] = key;
        __syncthreads();
        if (tid == 0) {
            unsigned long long mm = red[0];
#pragma unroll
            for (int i = 1; i < 4; ++i) { unsigned long long x = red[i]; mm = x < mm ? x : mm; }
            out[row] = (int)(mm & 0xFFFFFFFFull);
        }
        __syncthreads();
    }
}

extern "C" void kernel_launch(void* const* d_in, const int* in_sizes, int n_in,
                              void* d_out, int out_size, void* d_ws, size_t ws_size,
                              hipStream_t stream) {
    const float* input = (const float*)d_in[0];  // (8,4096,512) fp32
    const float* W     = (const float*)d_in[1];  // (16,512) fp32
    const float* cb    = (const float*)d_in[2];  // (8192,16) fp32
    int* out = (int*)d_out;                      // (32768,) int32 labels

    float*  partials = (float*)d_ws;                        // 8 MB
    float*  csq      = partials + 4 * (size_t)NROWS * CD;   // 32 KB
    f32x4*  csq4     = (f32x4*)(csq + CB);                  // 128 KB
    bf16x8* Bp       = (bf16x8*)((float*)csq4 + 4 * CB);    // 512 KB
    int*    counter  = (int*)(Bp + 32768);
    int*    queue    = counter + 16;                        // 128 KB

    prep_proj_kernel<<<2176, 256, 0, stream>>>(input, W, partials, cb, csq, csq4, Bp, counter);
    scan_kernel<<<NROWS / 64, 512, 0, stream>>>(partials, csq4, Bp, out, queue, counter);
    fallback_kernel<<<2048, 256, 0, stream>>>(partials, cb, csq, queue, counter, out);
}